// Round 1
// baseline (7864.818 us; speedup 1.0000x reference)
//
#include <hip/hip_runtime.h>
#include <hip/hip_bf16.h>

#define B_SZ 1024
#define T_SZ 128
#define D_SZ 256
#define H_SZ 512
#define C_SZ 1280   // 2H + D

typedef __attribute__((ext_vector_type(8))) short short8;   // bf16x8 frag
typedef __attribute__((ext_vector_type(4))) float f32x4;    // f32 accum frag

// ---- async global->LDS, 16B per lane -------------------------------------
__device__ inline void gll16(const void* g, void* l) {
  __builtin_amdgcn_global_load_lds(
      (const __attribute__((address_space(1))) unsigned int*)g,
      (__attribute__((address_space(3))) unsigned int*)l, 16, 0, 0);
}

// Stage a 64x64 bf16 tile (rows [row0,row0+64), cols [k0,k0+64) of a row-major
// src with strideElts bf16/row) into LDS [64][64] ushort (128B rows).
// Swizzle: 16B slot s of row r holds global k-slot s^(r&7)  (both-sides rule:
// linear LDS dest for global_load_lds + inverse-swizzled SOURCE address).
__device__ inline void stage64x64(const __hip_bfloat16* __restrict__ src,
                                  int strideElts, int row0, int k0,
                                  unsigned short* lds, int tid) {
  int wv = tid >> 6;
#pragma unroll
  for (int half = 0; half < 2; ++half) {
    int chunk = half * 256 + tid;          // 0..511 : 16B chunks of the tile
    int row = chunk >> 3;                  // 8 slots per 128B row
    int slot = chunk & 7;
    int ksrc = ((slot ^ (row & 7)) << 3);  // inverse-swizzled source k
    const __hip_bfloat16* g =
        src + (size_t)(row0 + row) * strideElts + (k0 + ksrc);
    // wave-uniform LDS base; HW adds lane*16
    unsigned short* l = lds + (size_t)(half * 256 + (wv << 6)) * 8;
    gll16((const void*)g, (void*)l);
  }
}

// read one 16x16x32 A/B fragment (16B) with matching swizzle
__device__ inline short8 ldfrag(const unsigned short* lds, int row, int slot) {
  int s = slot ^ (row & 7);
  return *(const short8*)(lds + row * 64 + s * 8);
}

// =============== K1: U = tanh(h @ W1 + b1) ================================
__global__ __launch_bounds__(256, 2) void k_mlp1(
    const __hip_bfloat16* __restrict__ hbf, const __hip_bfloat16* __restrict__ W1t,
    const float* __restrict__ b1, __hip_bfloat16* __restrict__ Ubf) {
  __shared__ __align__(16) unsigned short lA[64 * 64], lB[64 * 64];
  int tid = threadIdx.x, lane = tid & 63, wv = tid >> 6;
  int wr = wv >> 1, wc = wv & 1;
  int m0 = blockIdx.x << 6, n0 = blockIdx.y << 6;
  int lr = lane & 15, lg = lane >> 4;
  f32x4 acc[2][2] = {};
  for (int kt = 0; kt < H_SZ; kt += 64) {
    stage64x64(hbf, H_SZ, m0, kt, lA, tid);
    stage64x64(W1t, H_SZ, n0, kt, lB, tid);
    __syncthreads();
#pragma unroll
    for (int kk = 0; kk < 2; ++kk) {
      short8 a[2], b[2];
#pragma unroll
      for (int m = 0; m < 2; ++m) a[m] = ldfrag(lA, (wr << 5) + (m << 4) + lr, (kk << 2) + lg);
#pragma unroll
      for (int n = 0; n < 2; ++n) b[n] = ldfrag(lB, (wc << 5) + (n << 4) + lr, (kk << 2) + lg);
#pragma unroll
      for (int m = 0; m < 2; ++m)
#pragma unroll
        for (int n = 0; n < 2; ++n)
          acc[m][n] = __builtin_amdgcn_mfma_f32_16x16x32_bf16(a[m], b[n], acc[m][n], 0, 0, 0);
    }
    __syncthreads();
  }
#pragma unroll
  for (int m = 0; m < 2; ++m)
#pragma unroll
    for (int n = 0; n < 2; ++n) {
      int col = n0 + (wc << 5) + (n << 4) + lr;
      int r0 = m0 + (wr << 5) + (m << 4) + (lg << 2);
      float bi = b1[col];
#pragma unroll
      for (int r = 0; r < 4; ++r) {
        float v = tanhf(acc[m][n][r] + bi);
        Ubf[(size_t)(r0 + r) * H_SZ + col] = __float2bfloat16(v);
      }
    }
}

// =============== K2: h_ode = h + dt*(U @ W2 + b2); also x[:,t,:] -> bf16 ===
__global__ __launch_bounds__(256, 2) void k_mlp2(
    const __hip_bfloat16* __restrict__ Ubf, const __hip_bfloat16* __restrict__ W2t,
    const float* __restrict__ b2, const float* __restrict__ hf,
    float* __restrict__ hodef, __hip_bfloat16* __restrict__ hodeb,
    const float* __restrict__ x, const float* __restrict__ xtime,
    __hip_bfloat16* __restrict__ xstep, int t) {
  __shared__ __align__(16) unsigned short lA[64 * 64], lB[64 * 64];
  int tid = threadIdx.x, lane = tid & 63, wv = tid >> 6;
  int wr = wv >> 1, wc = wv & 1;
  int m0 = blockIdx.x << 6, n0 = blockIdx.y << 6;
  int lr = lane & 15, lg = lane >> 4;
  f32x4 acc[2][2] = {};
  for (int kt = 0; kt < H_SZ; kt += 64) {
    stage64x64(Ubf, H_SZ, m0, kt, lA, tid);
    stage64x64(W2t, H_SZ, n0, kt, lB, tid);
    __syncthreads();
#pragma unroll
    for (int kk = 0; kk < 2; ++kk) {
      short8 a[2], b[2];
#pragma unroll
      for (int m = 0; m < 2; ++m) a[m] = ldfrag(lA, (wr << 5) + (m << 4) + lr, (kk << 2) + lg);
#pragma unroll
      for (int n = 0; n < 2; ++n) b[n] = ldfrag(lB, (wc << 5) + (n << 4) + lr, (kk << 2) + lg);
#pragma unroll
      for (int m = 0; m < 2; ++m)
#pragma unroll
        for (int n = 0; n < 2; ++n)
          acc[m][n] = __builtin_amdgcn_mfma_f32_16x16x32_bf16(a[m], b[n], acc[m][n], 0, 0, 0);
    }
    __syncthreads();
  }
  float dt = (t == 0) ? 0.01f : (xtime[t] - xtime[t - 1]);
#pragma unroll
  for (int m = 0; m < 2; ++m)
#pragma unroll
    for (int n = 0; n < 2; ++n) {
      int col = n0 + (wc << 5) + (n << 4) + lr;
      int r0 = m0 + (wr << 5) + (m << 4) + (lg << 2);
      float bi = b2[col];
#pragma unroll
      for (int r = 0; r < 4; ++r) {
        size_t ix = (size_t)(r0 + r) * H_SZ + col;
        float v = hf[ix] + dt * (acc[m][n][r] + bi);
        hodef[ix] = v;
        hodeb[ix] = __float2bfloat16(v);
      }
    }
  // convert this step's x slice to bf16 (only the n-tile-0 column of blocks)
  if (blockIdx.y == 0) {
    for (int it = 0; it < 64; ++it) {
      int row = m0 + it;
      float xv = x[((size_t)row * T_SZ + t) * D_SZ + tid];
      xstep[(size_t)row * D_SZ + tid] = __float2bfloat16(xv);
    }
  }
}

// =============== K3: z|r = sigmoid(cat @ [Wz|Wr] + b); build A4 ===========
__global__ __launch_bounds__(256, 2) void k_gates(
    const __hip_bfloat16* __restrict__ hodeb, const __hip_bfloat16* __restrict__ hstdb,
    const __hip_bfloat16* __restrict__ xstep, const __hip_bfloat16* __restrict__ Wzrt,
    const float* __restrict__ bz, const float* __restrict__ br,
    const float* __restrict__ hodef, const float* __restrict__ hstdf,
    float* __restrict__ zf, __hip_bfloat16* __restrict__ A4) {
  __shared__ __align__(16) unsigned short lA[64 * 64], lB[64 * 64];
  int tid = threadIdx.x, lane = tid & 63, wv = tid >> 6;
  int wr = wv >> 1, wc = wv & 1;
  int m0 = blockIdx.x << 6, n0 = blockIdx.y << 6;
  int lr = lane & 15, lg = lane >> 4;
  f32x4 acc[2][2] = {};
  for (int kt = 0; kt < C_SZ; kt += 64) {
    const __hip_bfloat16* asrc;
    int astr, ak0;
    if (kt < 512)      { asrc = hodeb; astr = 512; ak0 = kt; }
    else if (kt < 1024){ asrc = hstdb; astr = 512; ak0 = kt - 512; }
    else               { asrc = xstep; astr = 256; ak0 = kt - 1024; }
    stage64x64(asrc, astr, m0, ak0, lA, tid);
    stage64x64(Wzrt, C_SZ, n0, kt, lB, tid);
    __syncthreads();
#pragma unroll
    for (int kk = 0; kk < 2; ++kk) {
      short8 a[2], b[2];
#pragma unroll
      for (int m = 0; m < 2; ++m) a[m] = ldfrag(lA, (wr << 5) + (m << 4) + lr, (kk << 2) + lg);
#pragma unroll
      for (int n = 0; n < 2; ++n) b[n] = ldfrag(lB, (wc << 5) + (n << 4) + lr, (kk << 2) + lg);
#pragma unroll
      for (int m = 0; m < 2; ++m)
#pragma unroll
        for (int n = 0; n < 2; ++n)
          acc[m][n] = __builtin_amdgcn_mfma_f32_16x16x32_bf16(a[m], b[n], acc[m][n], 0, 0, 0);
    }
    __syncthreads();
  }
  bool isz = (n0 < 512);
#pragma unroll
  for (int m = 0; m < 2; ++m)
#pragma unroll
    for (int n = 0; n < 2; ++n) {
      int cg = n0 + (wc << 5) + (n << 4) + lr;  // 0..1023
      int r0 = m0 + (wr << 5) + (m << 4) + (lg << 2);
      float bi = isz ? bz[cg] : br[cg - 512];
#pragma unroll
      for (int r = 0; r < 4; ++r) {
        int row = r0 + r;
        float g = 1.f / (1.f + expf(-(acc[m][n][r] + bi)));
        if (isz) {
          zf[(size_t)row * H_SZ + cg] = g;
        } else {
          int j = cg - 512;
          size_t ix = (size_t)row * H_SZ + j;
          A4[(size_t)row * 1024 + j]       = __float2bfloat16(hodef[ix] * g);
          A4[(size_t)row * 1024 + 512 + j] = __float2bfloat16(hstdf[ix] * g);
        }
      }
    }
}

// =============== K4: n = cat_r @ Wn + bn ; GRU update =====================
__global__ __launch_bounds__(256, 2) void k_new(
    const __hip_bfloat16* __restrict__ A4, const __hip_bfloat16* __restrict__ xstep,
    const __hip_bfloat16* __restrict__ Wnt, const float* __restrict__ bn,
    const float* __restrict__ zf, const float* __restrict__ hodef,
    float* __restrict__ hf, float* __restrict__ hstdf,
    __hip_bfloat16* __restrict__ hbf, __hip_bfloat16* __restrict__ hstdb) {
  __shared__ __align__(16) unsigned short lA[64 * 64], lBm[64 * 64], lBs[64 * 64];
  int tid = threadIdx.x, lane = tid & 63, wv = tid >> 6;
  int wr = wv >> 1, wc = wv & 1;
  int m0 = blockIdx.x << 6, n0 = blockIdx.y << 6;   // n0 over mean cols [0,512)
  int lr = lane & 15, lg = lane >> 4;
  f32x4 am[2][2] = {}, as[2][2] = {};
  for (int kt = 0; kt < C_SZ; kt += 64) {
    const __hip_bfloat16* asrc;
    int astr, ak0;
    if (kt < 1024) { asrc = A4;    astr = 1024; ak0 = kt; }
    else           { asrc = xstep; astr = 256;  ak0 = kt - 1024; }
    stage64x64(asrc, astr, m0, ak0, lA, tid);
    stage64x64(Wnt, C_SZ, n0, kt, lBm, tid);
    stage64x64(Wnt, C_SZ, n0 + 512, kt, lBs, tid);
    __syncthreads();
#pragma unroll
    for (int kk = 0; kk < 2; ++kk) {
      short8 a[2], bm[2], bs[2];
#pragma unroll
      for (int m = 0; m < 2; ++m) a[m] = ldfrag(lA, (wr << 5) + (m << 4) + lr, (kk << 2) + lg);
#pragma unroll
      for (int n = 0; n < 2; ++n) {
        bm[n] = ldfrag(lBm, (wc << 5) + (n << 4) + lr, (kk << 2) + lg);
        bs[n] = ldfrag(lBs, (wc << 5) + (n << 4) + lr, (kk << 2) + lg);
      }
#pragma unroll
      for (int m = 0; m < 2; ++m)
#pragma unroll
        for (int n = 0; n < 2; ++n) {
          am[m][n] = __builtin_amdgcn_mfma_f32_16x16x32_bf16(a[m], bm[n], am[m][n], 0, 0, 0);
          as[m][n] = __builtin_amdgcn_mfma_f32_16x16x32_bf16(a[m], bs[n], as[m][n], 0, 0, 0);
        }
    }
    __syncthreads();
  }
#pragma unroll
  for (int m = 0; m < 2; ++m)
#pragma unroll
    for (int n = 0; n < 2; ++n) {
      int c = n0 + (wc << 5) + (n << 4) + lr;   // 0..511
      int r0 = m0 + (wr << 5) + (m << 4) + (lg << 2);
      float bim = bn[c], bis = bn[512 + c];
#pragma unroll
      for (int r = 0; r < 4; ++r) {
        int row = r0 + r;
        size_t ix = (size_t)row * H_SZ + c;
        float nm = am[m][n][r] + bim;
        float ns = fabsf(as[m][n][r] + bis);
        float z = zf[ix], ho = hodef[ix], hs = hstdf[ix];
        float hn = (1.f - z) * nm + z * ho;
        float sn = fabsf((1.f - z) * ns + z * hs);
        hf[ix] = hn;
        hstdf[ix] = sn;
        hbf[ix] = __float2bfloat16(hn);
        hstdb[ix] = __float2bfloat16(sn);
      }
    }
}

// =============== prep: W[k][n] f32  ->  Wt[n][k] bf16 =====================
__global__ void k_wt(const float* __restrict__ W, __hip_bfloat16* __restrict__ Wt,
                     int K, int N, int ld) {
  size_t i = (size_t)blockIdx.x * 256 + threadIdx.x;
  if (i >= (size_t)K * N) return;
  int n = (int)(i / K), k = (int)(i % K);
  Wt[(size_t)n * ld + k] = __float2bfloat16(W[(size_t)k * N + n]);
}

extern "C" void kernel_launch(void* const* d_in, const int* in_sizes, int n_in,
                              void* d_out, int out_size, void* d_ws, size_t ws_size,
                              hipStream_t stream) {
  const float* x     = (const float*)d_in[0];
  const float* xtime = (const float*)d_in[1];
  const float* W1    = (const float*)d_in[2];
  const float* b1    = (const float*)d_in[3];
  const float* W2    = (const float*)d_in[4];
  const float* b2    = (const float*)d_in[5];
  const float* Wz    = (const float*)d_in[6];
  const float* bz    = (const float*)d_in[7];
  const float* Wr    = (const float*)d_in[8];
  const float* br    = (const float*)d_in[9];
  const float* Wn    = (const float*)d_in[10];
  const float* bn    = (const float*)d_in[11];

  char* p = (char*)d_ws;
  __hip_bfloat16* W1t   = (__hip_bfloat16*)(p + 0);         //  512x512
  __hip_bfloat16* W2t   = (__hip_bfloat16*)(p + 524288);    //  512x512
  __hip_bfloat16* Wzrt  = (__hip_bfloat16*)(p + 1048576);   // 1024x1280
  __hip_bfloat16* Wnt   = (__hip_bfloat16*)(p + 3670016);   // 1024x1280
  float*          hf    = (float*)(p + 6291456);            // 1024x512 state
  float*          hstdf = (float*)(p + 8388608);            // 1024x512 state
  float*          hodef = (float*)(p + 10485760);
  float*          zf    = (float*)(p + 12582912);
  __hip_bfloat16* hbf   = (__hip_bfloat16*)(p + 14680064);
  __hip_bfloat16* Ubf   = (__hip_bfloat16*)(p + 15728640);
  __hip_bfloat16* hodeb = (__hip_bfloat16*)(p + 16777216);
  __hip_bfloat16* hstdb = (__hip_bfloat16*)(p + 17825792);
  __hip_bfloat16* A4    = (__hip_bfloat16*)(p + 18874368);  // 1024x1024
  __hip_bfloat16* xstep = (__hip_bfloat16*)(p + 20971520);  // 1024x256

  // zero recurrent state (harness does not re-poison between replays)
  hipMemsetAsync(hf, 0, 2097152, stream);
  hipMemsetAsync(hstdf, 0, 2097152, stream);
  hipMemsetAsync(hbf, 0, 1048576, stream);
  hipMemsetAsync(hstdb, 0, 1048576, stream);

  // weights -> bf16, transposed to [N][K] so B-fragments load like A
  k_wt<<<(512 * 512 + 255) / 256, 256, 0, stream>>>(W1, W1t, 512, 512, 512);
  k_wt<<<(512 * 512 + 255) / 256, 256, 0, stream>>>(W2, W2t, 512, 512, 512);
  k_wt<<<(1280 * 512 + 255) / 256, 256, 0, stream>>>(Wz, Wzrt, 1280, 512, 1280);
  k_wt<<<(1280 * 512 + 255) / 256, 256, 0, stream>>>(Wr, Wzrt + (size_t)512 * 1280, 1280, 512, 1280);
  k_wt<<<(1280 * 1024 + 255) / 256, 256, 0, stream>>>(Wn, Wnt, 1280, 1024, 1280);

  for (int t = 0; t < T_SZ; ++t) {
    k_mlp1<<<dim3(16, 8), 256, 0, stream>>>(hbf, W1t, b1, Ubf);
    k_mlp2<<<dim3(16, 8), 256, 0, stream>>>(Ubf, W2t, b2, hf, hodef, hodeb, x, xtime, xstep, t);
    k_gates<<<dim3(16, 16), 256, 0, stream>>>(hodeb, hstdb, xstep, Wzrt, bz, br, hodef, hstdf, zf, A4);
    k_new<<<dim3(16, 8), 256, 0, stream>>>(A4, xstep, Wnt, bn, zf, hodef, hf, hstdf, hbf, hstdb);
  }

  hipMemcpyAsync(d_out, hf, 2097152, hipMemcpyDeviceToDevice, stream);
  hipMemcpyAsync((char*)d_out + 2097152, hstdf, 2097152, hipMemcpyDeviceToDevice, stream);
}

// Round 2
// 6939.539 us; speedup vs baseline: 1.1333x; 1.1333x over previous
//
#include <hip/hip_runtime.h>
#include <hip/hip_bf16.h>

#define B_SZ 1024
#define T_SZ 128
#define D_SZ 256
#define H_SZ 512
#define C_SZ 1280   // 2H + D

typedef __attribute__((ext_vector_type(8))) short short8;   // bf16x8 frag
typedef __attribute__((ext_vector_type(4))) float f32x4;    // f32 accum frag

__device__ inline void gll16(const void* g, void* l) {
  __builtin_amdgcn_global_load_lds(
      (const __attribute__((address_space(1))) unsigned int*)g,
      (__attribute__((address_space(3))) unsigned int*)l, 16, 0, 0);
}

__device__ inline f32x4 mfma16(short8 a, short8 b, f32x4 c) {
  return __builtin_amdgcn_mfma_f32_16x16x32_bf16(a, b, c, 0, 0, 0);
}

// Stage a ROWSx64 bf16 tile into LDS [ROWS][64] ushort (128B rows), slot-
// swizzled: 16B slot s of row r holds global k-slot s^(r&7). Linear LDS dest
// (global_load_lds requirement) + inverse-swizzled SOURCE address.
template <int ROWS>
__device__ inline void stageT(const __hip_bfloat16* __restrict__ src, int strideElts,
                              int row0, int k0, unsigned short* lds, int tid) {
  int wv = tid >> 6;
#pragma unroll
  for (int it = 0; it < (ROWS * 8) / 256; ++it) {
    int chunk = it * 256 + tid;
    int row = chunk >> 3, slot = chunk & 7;
    int ksrc = (slot ^ (row & 7)) << 3;
    const __hip_bfloat16* g = src + (size_t)(row0 + row) * strideElts + (k0 + ksrc);
    unsigned short* l = lds + (size_t)(it * 256 + (wv << 6)) * 8;  // wave-uniform base
    gll16((const void*)g, (void*)l);
  }
}

// read one 16x16x32 fragment (16B) with matching swizzle
__device__ inline short8 ldfrag(const unsigned short* lds, int row, int slot) {
  int s = slot ^ (row & 7);
  return *(const short8*)(lds + row * 64 + s * 8);
}

// one barrier per K-tile: drain my prefetch, join, pin scheduler
#define TILE_SYNC()                                  \
  do {                                               \
    asm volatile("s_waitcnt vmcnt(0)" ::: "memory"); \
    __builtin_amdgcn_s_barrier();                    \
    __builtin_amdgcn_sched_barrier(0);               \
  } while (0)

// =============== K1: U = tanh(h @ W1 + b1)   [1024x512, K=512] ============
// tile 32x64, grid (32,8): 256 blocks. 4 waves; wave wv owns n-frag wv.
__global__ __launch_bounds__(256, 2) void k_mlp1(
    const __hip_bfloat16* __restrict__ hbf, const __hip_bfloat16* __restrict__ W1t,
    const float* __restrict__ b1, __hip_bfloat16* __restrict__ Ubf) {
  __shared__ __align__(16) unsigned short lA[2][32 * 64], lB[2][64 * 64];
  int tid = threadIdx.x, lane = tid & 63, wv = tid >> 6;
  int m0 = blockIdx.x << 5, n0 = blockIdx.y << 6;
  int lr = lane & 15, lg = lane >> 4;
  f32x4 acc[2] = {};
  stageT<32>(hbf, H_SZ, m0, 0, lA[0], tid);
  stageT<64>(W1t, H_SZ, n0, 0, lB[0], tid);
  int cur = 0;
  for (int kt = 0; kt < 8; ++kt) {
    TILE_SYNC();
    if (kt + 1 < 8) {
      stageT<32>(hbf, H_SZ, m0, (kt + 1) << 6, lA[cur ^ 1], tid);
      stageT<64>(W1t, H_SZ, n0, (kt + 1) << 6, lB[cur ^ 1], tid);
    }
#pragma unroll
    for (int kk = 0; kk < 2; ++kk) {
      short8 b = ldfrag(lB[cur], (wv << 4) + lr, (kk << 2) + lg);
      short8 a0 = ldfrag(lA[cur], lr, (kk << 2) + lg);
      short8 a1 = ldfrag(lA[cur], 16 + lr, (kk << 2) + lg);
      acc[0] = mfma16(a0, b, acc[0]);
      acc[1] = mfma16(a1, b, acc[1]);
    }
    cur ^= 1;
  }
  int col = n0 + (wv << 4) + lr;
  float bi = b1[col];
#pragma unroll
  for (int m = 0; m < 2; ++m) {
    int r0 = m0 + (m << 4) + (lg << 2);
#pragma unroll
    for (int r = 0; r < 4; ++r) {
      float v = tanhf(acc[m][r] + bi);
      Ubf[(size_t)(r0 + r) * H_SZ + col] = __float2bfloat16(v);
    }
  }
}

// =============== K2: h_ode = h + dt*(U @ W2 + b2); x[:,t,:] -> bf16 =======
__global__ __launch_bounds__(256, 2) void k_mlp2(
    const __hip_bfloat16* __restrict__ Ubf, const __hip_bfloat16* __restrict__ W2t,
    const float* __restrict__ b2, const float* __restrict__ hf,
    float* __restrict__ hodef, __hip_bfloat16* __restrict__ hodeb,
    const float* __restrict__ x, const float* __restrict__ xtime,
    __hip_bfloat16* __restrict__ xstep, int t) {
  __shared__ __align__(16) unsigned short lA[2][32 * 64], lB[2][64 * 64];
  int tid = threadIdx.x, lane = tid & 63, wv = tid >> 6;
  int m0 = blockIdx.x << 5, n0 = blockIdx.y << 6;
  int lr = lane & 15, lg = lane >> 4;
  f32x4 acc[2] = {};
  stageT<32>(Ubf, H_SZ, m0, 0, lA[0], tid);
  stageT<64>(W2t, H_SZ, n0, 0, lB[0], tid);
  int cur = 0;
  for (int kt = 0; kt < 8; ++kt) {
    TILE_SYNC();
    if (kt + 1 < 8) {
      stageT<32>(Ubf, H_SZ, m0, (kt + 1) << 6, lA[cur ^ 1], tid);
      stageT<64>(W2t, H_SZ, n0, (kt + 1) << 6, lB[cur ^ 1], tid);
    }
#pragma unroll
    for (int kk = 0; kk < 2; ++kk) {
      short8 b = ldfrag(lB[cur], (wv << 4) + lr, (kk << 2) + lg);
      short8 a0 = ldfrag(lA[cur], lr, (kk << 2) + lg);
      short8 a1 = ldfrag(lA[cur], 16 + lr, (kk << 2) + lg);
      acc[0] = mfma16(a0, b, acc[0]);
      acc[1] = mfma16(a1, b, acc[1]);
    }
    cur ^= 1;
  }
  float dt = (t == 0) ? 0.01f : (xtime[t] - xtime[t - 1]);
  int col = n0 + (wv << 4) + lr;
  float bi = b2[col];
#pragma unroll
  for (int m = 0; m < 2; ++m) {
    int r0 = m0 + (m << 4) + (lg << 2);
#pragma unroll
    for (int r = 0; r < 4; ++r) {
      size_t ix = (size_t)(r0 + r) * H_SZ + col;
      float v = hf[ix] + dt * (acc[m][r] + bi);
      hodef[ix] = v;
      hodeb[ix] = __float2bfloat16(v);
    }
  }
  // convert this step's x slice to bf16 (one column of blocks does it)
  if (blockIdx.y == 0) {
#pragma unroll
    for (int it = 0; it < 32; ++it) {
      int row = m0 + it;
      float xv = x[((size_t)row * T_SZ + t) * D_SZ + tid];
      xstep[(size_t)row * D_SZ + tid] = __float2bfloat16(xv);
    }
  }
}

// A-source for the concat GEMMs (element offset ke into [h_ode|hstd|x])
__device__ inline const __hip_bfloat16* srcCat(int ke, const __hip_bfloat16* h1,
                                               const __hip_bfloat16* h2,
                                               const __hip_bfloat16* xs,
                                               int* str, int* k0) {
  if (ke < 512) { *str = 512; *k0 = ke; return h1; }
  if (ke < 1024) { *str = 512; *k0 = ke - 512; return h2; }
  *str = 256; *k0 = ke - 1024; return xs;
}

// =============== K3: z|r = sigmoid(cat @ [Wz|Wr] + b); build A4 ===========
// tile 64x64, grid (16,16): 256 blocks, N covers z(512)+r(512).
__global__ __launch_bounds__(256, 2) void k_gates(
    const __hip_bfloat16* __restrict__ hodeb, const __hip_bfloat16* __restrict__ hstdb,
    const __hip_bfloat16* __restrict__ xstep, const __hip_bfloat16* __restrict__ Wzrt,
    const float* __restrict__ bz, const float* __restrict__ br,
    const float* __restrict__ hodef, const float* __restrict__ hstdf,
    float* __restrict__ zf, __hip_bfloat16* __restrict__ A4) {
  __shared__ __align__(16) unsigned short lA[2][64 * 64], lB[2][64 * 64];
  int tid = threadIdx.x, lane = tid & 63, wv = tid >> 6;
  int wr = wv >> 1, wc = wv & 1;
  int m0 = blockIdx.x << 6, n0 = blockIdx.y << 6;
  int lr = lane & 15, lg = lane >> 4;
  f32x4 acc[2][2] = {};
  {
    int str, k0;
    const __hip_bfloat16* s = srcCat(0, hodeb, hstdb, xstep, &str, &k0);
    stageT<64>(s, str, m0, k0, lA[0], tid);
    stageT<64>(Wzrt, C_SZ, n0, 0, lB[0], tid);
  }
  int cur = 0;
  for (int kt = 0; kt < 20; ++kt) {
    TILE_SYNC();
    if (kt + 1 < 20) {
      int str, k0;
      const __hip_bfloat16* s = srcCat((kt + 1) << 6, hodeb, hstdb, xstep, &str, &k0);
      stageT<64>(s, str, m0, k0, lA[cur ^ 1], tid);
      stageT<64>(Wzrt, C_SZ, n0, (kt + 1) << 6, lB[cur ^ 1], tid);
    }
#pragma unroll
    for (int kk = 0; kk < 2; ++kk) {
      short8 a[2], b[2];
#pragma unroll
      for (int m = 0; m < 2; ++m) a[m] = ldfrag(lA[cur], (wr << 5) + (m << 4) + lr, (kk << 2) + lg);
#pragma unroll
      for (int n = 0; n < 2; ++n) b[n] = ldfrag(lB[cur], (wc << 5) + (n << 4) + lr, (kk << 2) + lg);
#pragma unroll
      for (int m = 0; m < 2; ++m)
#pragma unroll
        for (int n = 0; n < 2; ++n) acc[m][n] = mfma16(a[m], b[n], acc[m][n]);
    }
    cur ^= 1;
  }
  bool isz = (n0 < 512);
#pragma unroll
  for (int m = 0; m < 2; ++m)
#pragma unroll
    for (int n = 0; n < 2; ++n) {
      int cg = n0 + (wc << 5) + (n << 4) + lr;  // 0..1023
      int r0 = m0 + (wr << 5) + (m << 4) + (lg << 2);
      float bi = isz ? bz[cg] : br[cg - 512];
#pragma unroll
      for (int r = 0; r < 4; ++r) {
        int row = r0 + r;
        float g = 1.f / (1.f + expf(-(acc[m][n][r] + bi)));
        if (isz) {
          zf[(size_t)row * H_SZ + cg] = g;
        } else {
          int j = cg - 512;
          size_t ix = (size_t)row * H_SZ + j;
          A4[(size_t)row * 1024 + j]       = __float2bfloat16(hodef[ix] * g);
          A4[(size_t)row * 1024 + 512 + j] = __float2bfloat16(hstdf[ix] * g);
        }
      }
    }
}

// =============== K4: n = cat_r @ Wn + bn ; GRU update =====================
// tile 64x64, grid (16,16) over N=1024 (mean cols [0,512), std [512,1024)).
// mean/std epilogues are independent -> per-block branch, no pairing needed.
__global__ __launch_bounds__(256, 2) void k_new(
    const __hip_bfloat16* __restrict__ A4, const __hip_bfloat16* __restrict__ xstep,
    const __hip_bfloat16* __restrict__ Wnt, const float* __restrict__ bn,
    const float* __restrict__ zf, const float* __restrict__ hodef,
    float* __restrict__ hf, float* __restrict__ hstdf,
    __hip_bfloat16* __restrict__ hbf, __hip_bfloat16* __restrict__ hstdb) {
  __shared__ __align__(16) unsigned short lA[2][64 * 64], lB[2][64 * 64];
  int tid = threadIdx.x, lane = tid & 63, wv = tid >> 6;
  int wr = wv >> 1, wc = wv & 1;
  int m0 = blockIdx.x << 6, n0 = blockIdx.y << 6;
  int lr = lane & 15, lg = lane >> 4;
  f32x4 acc[2][2] = {};
  {
    stageT<64>(A4, 1024, m0, 0, lA[0], tid);
    stageT<64>(Wnt, C_SZ, n0, 0, lB[0], tid);
  }
  int cur = 0;
  for (int kt = 0; kt < 20; ++kt) {
    TILE_SYNC();
    if (kt + 1 < 20) {
      int ke = (kt + 1) << 6;
      if (ke < 1024) stageT<64>(A4, 1024, m0, ke, lA[cur ^ 1], tid);
      else           stageT<64>(xstep, D_SZ, m0, ke - 1024, lA[cur ^ 1], tid);
      stageT<64>(Wnt, C_SZ, n0, ke, lB[cur ^ 1], tid);
    }
#pragma unroll
    for (int kk = 0; kk < 2; ++kk) {
      short8 a[2], b[2];
#pragma unroll
      for (int m = 0; m < 2; ++m) a[m] = ldfrag(lA[cur], (wr << 5) + (m << 4) + lr, (kk << 2) + lg);
#pragma unroll
      for (int n = 0; n < 2; ++n) b[n] = ldfrag(lB[cur], (wc << 5) + (n << 4) + lr, (kk << 2) + lg);
#pragma unroll
      for (int m = 0; m < 2; ++m)
#pragma unroll
        for (int n = 0; n < 2; ++n) acc[m][n] = mfma16(a[m], b[n], acc[m][n]);
    }
    cur ^= 1;
  }
  bool ismean = (n0 < 512);
#pragma unroll
  for (int m = 0; m < 2; ++m)
#pragma unroll
    for (int n = 0; n < 2; ++n) {
      int c = n0 + (wc << 5) + (n << 4) + lr;  // 0..1023
      int r0 = m0 + (wr << 5) + (m << 4) + (lg << 2);
      float bi = bn[c];
#pragma unroll
      for (int r = 0; r < 4; ++r) {
        int row = r0 + r;
        if (ismean) {
          size_t ix = (size_t)row * H_SZ + c;
          float nm = acc[m][n][r] + bi;
          float z = zf[ix], ho = hodef[ix];
          float hn = (1.f - z) * nm + z * ho;
          hf[ix] = hn;
          hbf[ix] = __float2bfloat16(hn);
        } else {
          int j = c - 512;
          size_t ix = (size_t)row * H_SZ + j;
          float ns = fabsf(acc[m][n][r] + bi);
          float z = zf[ix], hs = hstdf[ix];
          float sn = fabsf((1.f - z) * ns + z * hs);
          hstdf[ix] = sn;
          hstdb[ix] = __float2bfloat16(sn);
        }
      }
    }
}

// =============== prep: W[k][n] f32  ->  Wt[n][k] bf16 =====================
__global__ void k_wt(const float* __restrict__ W, __hip_bfloat16* __restrict__ Wt,
                     int K, int N, int ld) {
  size_t i = (size_t)blockIdx.x * 256 + threadIdx.x;
  if (i >= (size_t)K * N) return;
  int n = (int)(i / K), k = (int)(i % K);
  Wt[(size_t)n * ld + k] = __float2bfloat16(W[(size_t)k * N + n]);
}

extern "C" void kernel_launch(void* const* d_in, const int* in_sizes, int n_in,
                              void* d_out, int out_size, void* d_ws, size_t ws_size,
                              hipStream_t stream) {
  const float* x     = (const float*)d_in[0];
  const float* xtime = (const float*)d_in[1];
  const float* W1    = (const float*)d_in[2];
  const float* b1    = (const float*)d_in[3];
  const float* W2    = (const float*)d_in[4];
  const float* b2    = (const float*)d_in[5];
  const float* Wz    = (const float*)d_in[6];
  const float* bz    = (const float*)d_in[7];
  const float* Wr    = (const float*)d_in[8];
  const float* br    = (const float*)d_in[9];
  const float* Wn    = (const float*)d_in[10];
  const float* bn    = (const float*)d_in[11];

  char* p = (char*)d_ws;
  __hip_bfloat16* W1t   = (__hip_bfloat16*)(p + 0);         //  512x512
  __hip_bfloat16* W2t   = (__hip_bfloat16*)(p + 524288);    //  512x512
  __hip_bfloat16* Wzrt  = (__hip_bfloat16*)(p + 1048576);   // 1024x1280
  __hip_bfloat16* Wnt   = (__hip_bfloat16*)(p + 3670016);   // 1024x1280
  float*          hf    = (float*)(p + 6291456);            // 1024x512 state
  float*          hstdf = (float*)(p + 8388608);            // 1024x512 state
  float*          hodef = (float*)(p + 10485760);
  float*          zf    = (float*)(p + 12582912);
  __hip_bfloat16* hbf   = (__hip_bfloat16*)(p + 14680064);
  __hip_bfloat16* Ubf   = (__hip_bfloat16*)(p + 15728640);
  __hip_bfloat16* hodeb = (__hip_bfloat16*)(p + 16777216);
  __hip_bfloat16* hstdb = (__hip_bfloat16*)(p + 17825792);
  __hip_bfloat16* A4    = (__hip_bfloat16*)(p + 18874368);  // 1024x1024
  __hip_bfloat16* xstep = (__hip_bfloat16*)(p + 20971520);  // 1024x256

  // zero recurrent state (harness does not re-poison between replays)
  hipMemsetAsync(hf, 0, 2097152, stream);
  hipMemsetAsync(hstdf, 0, 2097152, stream);
  hipMemsetAsync(hbf, 0, 1048576, stream);
  hipMemsetAsync(hstdb, 0, 1048576, stream);

  // weights -> bf16, transposed to [N][K] so B-fragments load like A
  k_wt<<<(512 * 512 + 255) / 256, 256, 0, stream>>>(W1, W1t, 512, 512, 512);
  k_wt<<<(512 * 512 + 255) / 256, 256, 0, stream>>>(W2, W2t, 512, 512, 512);
  k_wt<<<(1280 * 512 + 255) / 256, 256, 0, stream>>>(Wz, Wzrt, 1280, 512, 1280);
  k_wt<<<(1280 * 512 + 255) / 256, 256, 0, stream>>>(Wr, Wzrt + (size_t)512 * 1280, 1280, 512, 1280);
  k_wt<<<(1280 * 1024 + 255) / 256, 256, 0, stream>>>(Wn, Wnt, 1280, 1024, 1280);

  for (int t = 0; t < T_SZ; ++t) {
    k_mlp1<<<dim3(32, 8), 256, 0, stream>>>(hbf, W1t, b1, Ubf);
    k_mlp2<<<dim3(32, 8), 256, 0, stream>>>(Ubf, W2t, b2, hf, hodef, hodeb, x, xtime, xstep, t);
    k_gates<<<dim3(16, 16), 256, 0, stream>>>(hodeb, hstdb, xstep, Wzrt, bz, br, hodef, hstdf, zf, A4);
    k_new<<<dim3(16, 16), 256, 0, stream>>>(A4, xstep, Wnt, bn, zf, hodef, hf, hstdf, hbf, hstdb);
  }

  hipMemcpyAsync(d_out, hf, 2097152, hipMemcpyDeviceToDevice, stream);
  hipMemcpyAsync((char*)d_out + 2097152, hstdf, 2097152, hipMemcpyDeviceToDevice, stream);
}